// Round 18
// baseline (689.974 us; speedup 1.0000x reference)
//
#include <hip/hip_runtime.h>
#include <math.h>

#define HID 1024
#define NH 16
#define DH 64
#define SEQ 2048
#define NB 2
#define SPAN 512
#define PSTR 72    // ks/pos row stride (144 B); also band + P stride
#define VSTR 66    // vst stride (odd dword stride -> bank spread)

typedef __attribute__((ext_vector_type(8))) _Float16 f16x8;
typedef __attribute__((ext_vector_type(4))) _Float16 f16x4;
typedef __attribute__((ext_vector_type(4))) float f32x4;

// DPP ROW_ROR butterfly reduce over 16-lane rows (VALU pipe, no LDS traffic)
__device__ __forceinline__ float dpp_max16(float x) {
  int v;
  v = __builtin_amdgcn_update_dpp(0, __builtin_bit_cast(int, x), 0x128, 0xF, 0xF, true);
  x = fmaxf(x, __builtin_bit_cast(float, v));
  v = __builtin_amdgcn_update_dpp(0, __builtin_bit_cast(int, x), 0x124, 0xF, 0xF, true);
  x = fmaxf(x, __builtin_bit_cast(float, v));
  v = __builtin_amdgcn_update_dpp(0, __builtin_bit_cast(int, x), 0x122, 0xF, 0xF, true);
  x = fmaxf(x, __builtin_bit_cast(float, v));
  v = __builtin_amdgcn_update_dpp(0, __builtin_bit_cast(int, x), 0x121, 0xF, 0xF, true);
  return fmaxf(x, __builtin_bit_cast(float, v));
}
__device__ __forceinline__ float dpp_sum16(float x) {
  int v;
  v = __builtin_amdgcn_update_dpp(0, __builtin_bit_cast(int, x), 0x128, 0xF, 0xF, true);
  x += __builtin_bit_cast(float, v);
  v = __builtin_amdgcn_update_dpp(0, __builtin_bit_cast(int, x), 0x124, 0xF, 0xF, true);
  x += __builtin_bit_cast(float, v);
  v = __builtin_amdgcn_update_dpp(0, __builtin_bit_cast(int, x), 0x122, 0xF, 0xF, true);
  x += __builtin_bit_cast(float, v);
  v = __builtin_amdgcn_update_dpp(0, __builtin_bit_cast(int, x), 0x121, 0xF, 0xF, true);
  return x + __builtin_bit_cast(float, v);
}

// ---------------- f32 -> f16 convert (n4 = n/4)
__global__ __launch_bounds__(256)
void cvt16(const float* __restrict__ src, _Float16* __restrict__ dst, int n4) {
  int i = blockIdx.x * 256 + threadIdx.x;
  const int stride = gridDim.x * 256;
  for (; i < n4; i += stride) {
    float4 v = ((const float4*)src)[i];
    f16x4 o;
    o.x = (_Float16)v.x; o.y = (_Float16)v.y;
    o.z = (_Float16)v.z; o.w = (_Float16)v.w;
    ((f16x4*)dst)[i] = o;
  }
}

// ---------------- transpose+convert: Wt[z][n][k] = (f16) W_z[k][n]
__global__ __launch_bounds__(256)
void transW(const float* __restrict__ W0, const float* __restrict__ W1,
            const float* __restrict__ W2, const float* __restrict__ W3,
            const float* __restrict__ W4, _Float16* __restrict__ Wt) {
  const int z = blockIdx.z;
  const float* W = z == 0 ? W0 : z == 1 ? W1 : z == 2 ? W2 : z == 3 ? W3 : W4;
  _Float16* out = Wt + (size_t)z * HID * HID;
  const int k0 = blockIdx.x * 64, n0 = blockIdx.y * 64;
  __shared__ _Float16 t[64][72];
  const int tid = threadIdx.x;
  #pragma unroll
  for (int p = 0; p < 4; ++p) {
    int idx = tid + p * 256;
    int row = idx >> 4, c4 = idx & 15;
    float4 v = *(const float4*)&W[(size_t)(k0 + row) * HID + n0 + c4 * 4];
    t[c4 * 4 + 0][row] = (_Float16)v.x;
    t[c4 * 4 + 1][row] = (_Float16)v.y;
    t[c4 * 4 + 2][row] = (_Float16)v.z;
    t[c4 * 4 + 3][row] = (_Float16)v.w;
  }
  __syncthreads();
  #pragma unroll
  for (int p = 0; p < 2; ++p) {
    int idx = tid + p * 256;
    int row = idx >> 3, c8 = idx & 7;
    *(f16x8*)&out[(size_t)(n0 + row) * HID + k0 + c8 * 8] = *(const f16x8*)&t[row][c8 * 8];
  }
}

// ---------------- fused f16-MFMA GEMM for all 5 projections (z selects)
__global__ __launch_bounds__(256)
void gemm_all(const _Float16* __restrict__ A16, const _Float16* __restrict__ R16,
              const _Float16* __restrict__ Wt,
              const float* __restrict__ bq, const float* __restrict__ bk,
              const float* __restrict__ bv, const float* __restrict__ bpq,
              _Float16* __restrict__ qo, _Float16* __restrict__ ko,
              _Float16* __restrict__ vo, _Float16* __restrict__ pko,
              _Float16* __restrict__ pqo, float qscale, float pqscale) {
  const int z = blockIdx.z;
  if (z >= 3 && blockIdx.y >= 8) return;          // pos GEMMs: M=1024 only
  const _Float16* A = (z < 3) ? A16 : R16;
  const _Float16* B = Wt + (size_t)z * HID * HID;
  const float* bias = z == 0 ? bq : z == 1 ? bk : z == 2 ? bv : z == 3 ? (const float*)nullptr : bpq;
  _Float16* C = z == 0 ? qo : z == 1 ? ko : z == 2 ? vo : z == 3 ? pko : pqo;
  const float scale = z == 0 ? qscale : z == 4 ? pqscale : 1.0f;

  __shared__ _Float16 As[128 * 40];
  __shared__ _Float16 Bs[128 * 40];
  const int tid = threadIdx.x;
  const int m0 = blockIdx.y * 128, n0 = blockIdx.x * 128;
  const int w = tid >> 6, l = tid & 63;
  const int wr = w >> 1, wc = w & 1;
  const int lr = l & 15, lh = l >> 4;

  f32x4 acc[4][4];
  #pragma unroll
  for (int m = 0; m < 4; ++m)
    #pragma unroll
    for (int n = 0; n < 4; ++n)
      acc[m][n] = (f32x4){0.f, 0.f, 0.f, 0.f};

  for (int k0 = 0; k0 < HID; k0 += 32) {
    __syncthreads();
    #pragma unroll
    for (int p = 0; p < 2; ++p) {
      int idx = tid + p * 256;
      int row = idx >> 2, c = idx & 3;
      *(f16x8*)&As[row * 40 + c * 8] = *(const f16x8*)&A[(size_t)(m0 + row) * HID + k0 + c * 8];
      *(f16x8*)&Bs[row * 40 + c * 8] = *(const f16x8*)&B[(size_t)(n0 + row) * HID + k0 + c * 8];
    }
    __syncthreads();

    f16x8 af[4], bfr[4];
    #pragma unroll
    for (int m = 0; m < 4; ++m)
      af[m] = *(const f16x8*)&As[(wr * 64 + m * 16 + lr) * 40 + lh * 8];
    #pragma unroll
    for (int n = 0; n < 4; ++n)
      bfr[n] = *(const f16x8*)&Bs[(wc * 64 + n * 16 + lr) * 40 + lh * 8];
    #pragma unroll
    for (int m = 0; m < 4; ++m)
      #pragma unroll
      for (int n = 0; n < 4; ++n)
        acc[m][n] = __builtin_amdgcn_mfma_f32_16x16x32_f16(af[m], bfr[n], acc[m][n], 0, 0, 0);
  }

  #pragma unroll
  for (int n = 0; n < 4; ++n) {
    int col = n0 + wc * 64 + n * 16 + lr;
    float bv_ = bias ? bias[col] : 0.0f;
    #pragma unroll
    for (int m = 0; m < 4; ++m)
      #pragma unroll
      for (int r = 0; r < 4; ++r) {
        int row = m0 + wr * 64 + m * 16 + lh * 4 + r;
        C[(size_t)row * HID + col] = (_Float16)((acc[m][n][r] + bv_) * scale);
      }
  }
}

// ---------------- fused disentangled attention, f16 MFMA, fp32 softmax
// r16 structure (measured best) + P tile fused into the dead ks region
// (all ks reads complete before B3; restaging guarded by B1) -> LDS 54,528 B
// -> 3 blocks/CU possible.
__global__ __launch_bounds__(256, 3)
void attn_mfma(const _Float16* __restrict__ qg, const _Float16* __restrict__ kg,
               const _Float16* __restrict__ vg, const _Float16* __restrict__ pkg,
               const _Float16* __restrict__ pqg, float* __restrict__ outg) {
  const int q0 = blockIdx.x * 64;
  const int h = blockIdx.y, b = blockIdx.z;
  const int tid = threadIdx.x;
  const int w = tid >> 6, l = tid & 63;
  const int lr = l & 15, lh = l >> 4;
  const size_t hoff = (size_t)h * DH;

  __shared__ _Float16 ks[64 * PSTR];    // K tile; reused as P tile after B3
  __shared__ _Float16 vst[64 * VSTR];   // V^T: vst[d][ki]
  __shared__ _Float16 posA[128 * PSTR]; // pos_k rows; aliased by c2pT[ri][row]
  __shared__ _Float16 posB[128 * PSTR]; // pos_q rows; aliased by p2cT[ri][row]
  _Float16* c2pT = posA;
  _Float16* p2cT = posB;
  _Float16* ps = ks;                    // P lives in dead ks region (cols 0..63)

  // Q fragments straight from global (loop-invariant)
  f16x8 aq[2];
  #pragma unroll
  for (int kk = 0; kk < 2; ++kk)
    aq[kk] = *(const f16x8*)&qg[((size_t)(b * SEQ + q0 + w * 16 + lr)) * HID + hoff + kk * 32 + lh * 8];

  f32x4 accO[4];
  float m_[4], l_[4];
  #pragma unroll
  for (int r = 0; r < 4; ++r) { m_[r] = -1e30f; l_[r] = 0.0f; }  // l_ per-lane partial
  #pragma unroll
  for (int nt = 0; nt < 4; ++nt) accO[nt] = (f32x4){0.f, 0.f, 0.f, 0.f};

  const int vd4 = tid & 15, vkq = tid >> 4;   // V-staging: 4d x 4k block per thread

  // ---- T14 prefetch registers ----
  f16x8 kreg[2], pAreg[4], pBreg[4];
  f16x4 vreg[4];
  {
    // prologue: load tile 0
    #pragma unroll
    for (int p = 0; p < 2; ++p) {
      int idx = tid + p * 256, row = idx >> 3, c = idx & 7;
      kreg[p] = *(const f16x8*)&kg[((size_t)(b * SEQ + row)) * HID + hoff + c * 8];
    }
    #pragma unroll
    for (int j = 0; j < 4; ++j)
      vreg[j] = *(const f16x4*)&vg[((size_t)(b * SEQ + vkq * 4 + j)) * HID + hoff + vd4 * 4];
    int r_lo1 = min(max(q0 - 63 + SPAN, 0), 2 * SPAN - 1);
    int r_hi1 = min(max(q0 + 63 + SPAN, 0), 2 * SPAN - 1);
    int nr1 = r_hi1 - r_lo1 + 1;
    #pragma unroll
    for (int p = 0; p < 4; ++p) {
      int idx = tid + p * 256;
      if (idx < nr1 * 8) {
        int row = idx >> 3, c = idx & 7;
        size_t gb = ((size_t)(r_lo1 + row)) * HID + hoff + c * 8;
        pAreg[p] = *(const f16x8*)&pkg[gb];
        pBreg[p] = *(const f16x8*)&pqg[gb];
      }
    }
  }

  for (int k0 = 0; k0 < SEQ; k0 += 64) {
    const int r_lo = min(max(q0 - k0 - 63 + SPAN, 0), 2 * SPAN - 1);
    const int r_hi = min(max(q0 - k0 + 63 + SPAN, 0), 2 * SPAN - 1);
    const int nr = r_hi - r_lo + 1;                // <= 127
    const int bt_lim = (nr + 15) >> 4;

    __syncthreads();   // B1: prev-tile PV reads (vst, ps-in-ks) done
    // ---- LDS writes from prefetched registers ----
    #pragma unroll
    for (int p = 0; p < 2; ++p) {
      int idx = tid + p * 256, row = idx >> 3, c = idx & 7;
      *(f16x8*)&ks[row * PSTR + c * 8] = kreg[p];
    }
    #pragma unroll
    for (int di = 0; di < 4; ++di) {
      f16x4 wv;
      wv.x = vreg[0][di]; wv.y = vreg[1][di]; wv.z = vreg[2][di]; wv.w = vreg[3][di];
      *(f16x4*)&vst[(vd4 * 4 + di) * VSTR + vkq * 4] = wv;
    }
    #pragma unroll
    for (int p = 0; p < 4; ++p) {
      int idx = tid + p * 256;
      if (idx < nr * 8) {
        int row = idx >> 3, c = idx & 7;
        *(f16x8*)&posA[row * PSTR + c * 8] = pAreg[p];
        *(f16x8*)&posB[row * PSTR + c * 8] = pBreg[p];
      }
    }
    // ---- issue next-tile global loads (latency hides under compute) ----
    const int k1 = k0 + 64;
    if (k1 < SEQ) {
      #pragma unroll
      for (int p = 0; p < 2; ++p) {
        int idx = tid + p * 256, row = idx >> 3, c = idx & 7;
        kreg[p] = *(const f16x8*)&kg[((size_t)(b * SEQ + k1 + row)) * HID + hoff + c * 8];
      }
      #pragma unroll
      for (int j = 0; j < 4; ++j)
        vreg[j] = *(const f16x4*)&vg[((size_t)(b * SEQ + k1 + vkq * 4 + j)) * HID + hoff + vd4 * 4];
      int r_lo1 = min(max(q0 - k1 - 63 + SPAN, 0), 2 * SPAN - 1);
      int r_hi1 = min(max(q0 - k1 + 63 + SPAN, 0), 2 * SPAN - 1);
      int nr1 = r_hi1 - r_lo1 + 1;
      #pragma unroll
      for (int p = 0; p < 4; ++p) {
        int idx = tid + p * 256;
        if (idx < nr1 * 8) {
          int row = idx >> 3, c = idx & 7;
          size_t gb = ((size_t)(r_lo1 + row)) * HID + hoff + c * 8;
          pAreg[p] = *(const f16x8*)&pkg[gb];
          pBreg[p] = *(const f16x8*)&pqg[gb];
        }
      }
    }
    __syncthreads();   // B2: ks/vst/pos visible

    // ---- MFMA phase (all ks reads happen here, before B3) ----
    __builtin_amdgcn_s_setprio(1);
    f16x8 ak[2];
    #pragma unroll
    for (int kk = 0; kk < 2; ++kk)
      ak[kk] = *(const f16x8*)&ks[(w * 16 + lr) * PSTR + kk * 32 + lh * 8];

    f32x4 sqk[4];
    #pragma unroll
    for (int nt = 0; nt < 4; ++nt) sqk[nt] = (f32x4){0.f, 0.f, 0.f, 0.f};
    #pragma unroll
    for (int nt = 0; nt < 4; ++nt)
      #pragma unroll
      for (int kk = 0; kk < 2; ++kk) {
        f16x8 bk = *(const f16x8*)&ks[(nt * 16 + lr) * PSTR + kk * 32 + lh * 8];
        sqk[nt] = __builtin_amdgcn_mfma_f32_16x16x32_f16(aq[kk], bk, sqk[nt], 0, 0, 0);
      }

    f32x4 bandA[8], bandB[8];
    #pragma unroll
    for (int bt = 0; bt < 8; ++bt) {
      bandA[bt] = (f32x4){0.f, 0.f, 0.f, 0.f};
      bandB[bt] = (f32x4){0.f, 0.f, 0.f, 0.f};
    }
    #pragma unroll
    for (int bt = 0; bt < 8; ++bt)
      if (bt < bt_lim)
        #pragma unroll
        for (int kk = 0; kk < 2; ++kk) {
          f16x8 bp = *(const f16x8*)&posA[(bt * 16 + lr) * PSTR + kk * 32 + lh * 8];
          bandA[bt] = __builtin_amdgcn_mfma_f32_16x16x32_f16(aq[kk], bp, bandA[bt], 0, 0, 0);
        }
    #pragma unroll
    for (int bt = 0; bt < 8; ++bt)
      if (bt < bt_lim)
        #pragma unroll
        for (int kk = 0; kk < 2; ++kk) {
          f16x8 bp = *(const f16x8*)&posB[(bt * 16 + lr) * PSTR + kk * 32 + lh * 8];
          bandB[bt] = __builtin_amdgcn_mfma_f32_16x16x32_f16(ak[kk], bp, bandB[bt], 0, 0, 0);
        }
    __builtin_amdgcn_s_setprio(0);
    __syncthreads();  // B3: pos frag reads + ALL ks reads done (ks now dead)

    // ---- write bands TRANSPOSED [ri][row] via cvt_pkrtz (uint2 b64) ----
    #pragma unroll
    for (int bt = 0; bt < 8; ++bt)
      if (bt < bt_lim) {
        uint2 wa, wb;
        wa.x = __builtin_bit_cast(unsigned, __builtin_amdgcn_cvt_pkrtz(bandA[bt][0], bandA[bt][1]));
        wa.y = __builtin_bit_cast(unsigned, __builtin_amdgcn_cvt_pkrtz(bandA[bt][2], bandA[bt][3]));
        wb.x = __builtin_bit_cast(unsigned, __builtin_amdgcn_cvt_pkrtz(bandB[bt][0], bandB[bt][1]));
        wb.y = __builtin_bit_cast(unsigned, __builtin_amdgcn_cvt_pkrtz(bandB[bt][2], bandB[bt][3]));
        *(uint2*)&c2pT[(bt * 16 + lr) * PSTR + w * 16 + lh * 4] = wa;
        *(uint2*)&p2cT[(bt * 16 + lr) * PSTR + w * 16 + lh * 4] = wb;
      }
    __syncthreads();   // B4: bands visible to all waves

    // ---- assemble scores, online softmax (raw v_exp_f32, DPP), write P ----
    const int rfix = (q0 - k0 + SPAN) - r_lo;
    float pc1[4];
    if (nr == 1) {
      #pragma unroll
      for (int nt = 0; nt < 4; ++nt) pc1[nt] = (float)p2cT[nt * 16 + lr];
    }
    #pragma unroll
    for (int r = 0; r < 4; ++r) {
      int qi = w * 16 + lh * 4 + r;
      float sc[4];
      if (nr == 1) {
        float cA = (float)c2pT[qi];
        #pragma unroll
        for (int nt = 0; nt < 4; ++nt)
          sc[nt] = sqk[nt][r] + cA + pc1[nt];
      } else {
        #pragma unroll
        for (int nt = 0; nt < 4; ++nt) {
          int ki = nt * 16 + lr;
          int ri = min(max(rfix + qi - ki, 0), nr - 1);
          sc[nt] = sqk[nt][r] + (float)c2pT[ri * PSTR + qi] + (float)p2cT[ri * PSTR + ki];
        }
      }
      float mx = dpp_max16(fmaxf(fmaxf(sc[0], sc[1]), fmaxf(sc[2], sc[3])));
      float mnew = fmaxf(m_[r], mx);
      float alpha = __builtin_amdgcn_exp2f(m_[r] - mnew);   // raw v_exp_f32
      float s0 = 0.0f;
      #pragma unroll
      for (int nt = 0; nt < 4; ++nt) {
        float p = __builtin_amdgcn_exp2f(sc[nt] - mnew);    // raw v_exp_f32
        s0 += p;
        ps[qi * PSTR + ((nt ^ lh) * 16) + lr] = (_Float16)p;   // P into dead ks
      }
      l_[r] = l_[r] * alpha + s0;
      m_[r] = mnew;
      #pragma unroll
      for (int nt = 0; nt < 4; ++nt) accO[nt][r] *= alpha;
    }
    // no barrier: P rows and pa reads are wave-local; vst unchanged since stage

    // ---- PV: O[16 q-rows][64 d] += P[16][64] @ V[64][64] ----
    __builtin_amdgcn_s_setprio(1);
    f16x8 pa[2];
    const int keyr = lr >> 2;                     // (row>>2)&3 for row = w*16+lr
    #pragma unroll
    for (int kk = 0; kk < 2; ++kk) {
      int blk = (kk * 2 + (lh >> 1)) ^ keyr;      // inverse of nt^lh write perm
      pa[kk] = *(const f16x8*)&ps[(w * 16 + lr) * PSTR + blk * 16 + (lh & 1) * 8];
    }
    #pragma unroll
    for (int nt = 0; nt < 4; ++nt)
      #pragma unroll
      for (int kk = 0; kk < 2; ++kk) {
        f16x8 vb = *(const f16x8*)&vst[(nt * 16 + lr) * VSTR + kk * 32 + lh * 8];
        accO[nt] = __builtin_amdgcn_mfma_f32_16x16x32_f16(pa[kk], vb, accO[nt], 0, 0, 0);
      }
    __builtin_amdgcn_s_setprio(0);
  }

  // ---- output (reduce per-lane partial l via DPP) ----
  #pragma unroll
  for (int r = 0; r < 4; ++r) {
    float inv = 1.0f / dpp_sum16(l_[r]);
    int row = q0 + w * 16 + lh * 4 + r;
    #pragma unroll
    for (int nt = 0; nt < 4; ++nt) {
      int col = h * DH + nt * 16 + lr;
      outg[((size_t)(b * SEQ + row)) * HID + col] = accO[nt][r] * inv;
    }
  }
}

extern "C" void kernel_launch(void* const* d_in, const int* in_sizes, int n_in,
                              void* d_out, int out_size, void* d_ws, size_t ws_size,
                              hipStream_t stream) {
  const float* hs  = (const float*)d_in[0];
  const float* rel = (const float*)d_in[1];
  const float* Wq  = (const float*)d_in[2];
  const float* bq  = (const float*)d_in[3];
  const float* Wk  = (const float*)d_in[4];
  const float* bk  = (const float*)d_in[5];
  const float* Wv  = (const float*)d_in[6];
  const float* bv  = (const float*)d_in[7];
  const float* Wpk = (const float*)d_in[8];
  const float* Wpq = (const float*)d_in[9];
  const float* bpq = (const float*)d_in[10];
  float* out = (float*)d_out;

  _Float16* ws = (_Float16*)d_ws;
  _Float16* q   = ws;                         // 4096x1024 f16
  _Float16* k   = ws + 4194304;
  _Float16* v   = ws + 8388608;
  _Float16* pk  = ws + 12582912;              // 1024x1024 f16
  _Float16* pq  = ws + 13631488;
  _Float16* A16 = ws + 14680064;              // hs f16
  _Float16* R16 = ws + 18874368;              // rel f16
  _Float16* Wt  = ws + 19922944;              // 5x 1024x1024 f16 (transposed W)

  const float LOG2E = 1.44269504088896f;
  // log2(e) folded into q and pos_q so softmax runs on raw v_exp_f32:
  // qk, c2p scale via q; p2c scale via pos_q -> ALL score terms in log2 units.
  const float qscale  = 0.125f * LOG2E;                          // 1/sqrt(64) * log2e
  const float pqscale = (1.0f / (8.0f * sqrtf(192.0f))) * LOG2E;

  dim3 blk(256);
  cvt16<<<dim3(2048), blk, 0, stream>>>(hs, A16, (NB * SEQ * HID) / 4);
  cvt16<<<dim3(1024), blk, 0, stream>>>(rel, R16, (2 * SPAN * HID) / 4);
  transW<<<dim3(16, 16, 5), blk, 0, stream>>>(Wq, Wk, Wv, Wpk, Wpq, Wt);

  gemm_all<<<dim3(HID / 128, (NB * SEQ) / 128, 5), blk, 0, stream>>>(
      A16, R16, Wt, bq, bk, bv, bpq, q, k, v, pk, pq, qscale, pqscale);

  dim3 ga(SEQ / 64, NH, NB);
  attn_mfma<<<ga, blk, 0, stream>>>(q, k, v, pk, pq, out);
}

// Round 19
// 304.057 us; speedup vs baseline: 2.2692x; 2.2692x over previous
//
#include <hip/hip_runtime.h>
#include <math.h>

#define HID 1024
#define NH 16
#define DH 64
#define SEQ 2048
#define NB 2
#define SPAN 512
#define PSTR 72    // ks/ps/pos row stride (144 B)
#define VSTR 66    // vst stride (odd dword stride -> bank spread)

typedef __attribute__((ext_vector_type(8))) _Float16 f16x8;
typedef __attribute__((ext_vector_type(4))) _Float16 f16x4;
typedef __attribute__((ext_vector_type(4))) float f32x4;

// DPP ROW_ROR butterfly reduce over 16-lane rows (VALU pipe, no LDS traffic)
__device__ __forceinline__ float dpp_max16(float x) {
  int v;
  v = __builtin_amdgcn_update_dpp(0, __builtin_bit_cast(int, x), 0x128, 0xF, 0xF, true);
  x = fmaxf(x, __builtin_bit_cast(float, v));
  v = __builtin_amdgcn_update_dpp(0, __builtin_bit_cast(int, x), 0x124, 0xF, 0xF, true);
  x = fmaxf(x, __builtin_bit_cast(float, v));
  v = __builtin_amdgcn_update_dpp(0, __builtin_bit_cast(int, x), 0x122, 0xF, 0xF, true);
  x = fmaxf(x, __builtin_bit_cast(float, v));
  v = __builtin_amdgcn_update_dpp(0, __builtin_bit_cast(int, x), 0x121, 0xF, 0xF, true);
  return fmaxf(x, __builtin_bit_cast(float, v));
}
__device__ __forceinline__ float dpp_sum16(float x) {
  int v;
  v = __builtin_amdgcn_update_dpp(0, __builtin_bit_cast(int, x), 0x128, 0xF, 0xF, true);
  x += __builtin_bit_cast(float, v);
  v = __builtin_amdgcn_update_dpp(0, __builtin_bit_cast(int, x), 0x124, 0xF, 0xF, true);
  x += __builtin_bit_cast(float, v);
  v = __builtin_amdgcn_update_dpp(0, __builtin_bit_cast(int, x), 0x122, 0xF, 0xF, true);
  x += __builtin_bit_cast(float, v);
  v = __builtin_amdgcn_update_dpp(0, __builtin_bit_cast(int, x), 0x121, 0xF, 0xF, true);
  return x + __builtin_bit_cast(float, v);
}

// ---------------- f32 -> f16 convert (n4 = n/4)
__global__ __launch_bounds__(256)
void cvt16(const float* __restrict__ src, _Float16* __restrict__ dst, int n4) {
  int i = blockIdx.x * 256 + threadIdx.x;
  const int stride = gridDim.x * 256;
  for (; i < n4; i += stride) {
    float4 v = ((const float4*)src)[i];
    f16x4 o;
    o.x = (_Float16)v.x; o.y = (_Float16)v.y;
    o.z = (_Float16)v.z; o.w = (_Float16)v.w;
    ((f16x4*)dst)[i] = o;
  }
}

// ---------------- transpose+convert: Wt[z][n][k] = (f16) W_z[k][n]
__global__ __launch_bounds__(256)
void transW(const float* __restrict__ W0, const float* __restrict__ W1,
            const float* __restrict__ W2, const float* __restrict__ W3,
            const float* __restrict__ W4, _Float16* __restrict__ Wt) {
  const int z = blockIdx.z;
  const float* W = z == 0 ? W0 : z == 1 ? W1 : z == 2 ? W2 : z == 3 ? W3 : W4;
  _Float16* out = Wt + (size_t)z * HID * HID;
  const int k0 = blockIdx.x * 64, n0 = blockIdx.y * 64;
  __shared__ _Float16 t[64][72];
  const int tid = threadIdx.x;
  #pragma unroll
  for (int p = 0; p < 4; ++p) {
    int idx = tid + p * 256;
    int row = idx >> 4, c4 = idx & 15;
    float4 v = *(const float4*)&W[(size_t)(k0 + row) * HID + n0 + c4 * 4];
    t[c4 * 4 + 0][row] = (_Float16)v.x;
    t[c4 * 4 + 1][row] = (_Float16)v.y;
    t[c4 * 4 + 2][row] = (_Float16)v.z;
    t[c4 * 4 + 3][row] = (_Float16)v.w;
  }
  __syncthreads();
  #pragma unroll
  for (int p = 0; p < 2; ++p) {
    int idx = tid + p * 256;
    int row = idx >> 3, c8 = idx & 7;
    *(f16x8*)&out[(size_t)(n0 + row) * HID + k0 + c8 * 8] = *(const f16x8*)&t[row][c8 * 8];
  }
}

// ---------------- fused f16-MFMA GEMM for all 5 projections (z selects)
__global__ __launch_bounds__(256)
void gemm_all(const _Float16* __restrict__ A16, const _Float16* __restrict__ R16,
              const _Float16* __restrict__ Wt,
              const float* __restrict__ bq, const float* __restrict__ bk,
              const float* __restrict__ bv, const float* __restrict__ bpq,
              _Float16* __restrict__ qo, _Float16* __restrict__ ko,
              _Float16* __restrict__ vo, _Float16* __restrict__ pko,
              _Float16* __restrict__ pqo, float qscale, float pqscale) {
  const int z = blockIdx.z;
  if (z >= 3 && blockIdx.y >= 8) return;          // pos GEMMs: M=1024 only
  const _Float16* A = (z < 3) ? A16 : R16;
  const _Float16* B = Wt + (size_t)z * HID * HID;
  const float* bias = z == 0 ? bq : z == 1 ? bk : z == 2 ? bv : z == 3 ? (const float*)nullptr : bpq;
  _Float16* C = z == 0 ? qo : z == 1 ? ko : z == 2 ? vo : z == 3 ? pko : pqo;
  const float scale = z == 0 ? qscale : z == 4 ? pqscale : 1.0f;

  __shared__ _Float16 As[128 * 40];
  __shared__ _Float16 Bs[128 * 40];
  const int tid = threadIdx.x;
  const int m0 = blockIdx.y * 128, n0 = blockIdx.x * 128;
  const int w = tid >> 6, l = tid & 63;
  const int wr = w >> 1, wc = w & 1;
  const int lr = l & 15, lh = l >> 4;

  f32x4 acc[4][4];
  #pragma unroll
  for (int m = 0; m < 4; ++m)
    #pragma unroll
    for (int n = 0; n < 4; ++n)
      acc[m][n] = (f32x4){0.f, 0.f, 0.f, 0.f};

  for (int k0 = 0; k0 < HID; k0 += 32) {
    __syncthreads();
    #pragma unroll
    for (int p = 0; p < 2; ++p) {
      int idx = tid + p * 256;
      int row = idx >> 2, c = idx & 3;
      *(f16x8*)&As[row * 40 + c * 8] = *(const f16x8*)&A[(size_t)(m0 + row) * HID + k0 + c * 8];
      *(f16x8*)&Bs[row * 40 + c * 8] = *(const f16x8*)&B[(size_t)(n0 + row) * HID + k0 + c * 8];
    }
    __syncthreads();

    f16x8 af[4], bfr[4];
    #pragma unroll
    for (int m = 0; m < 4; ++m)
      af[m] = *(const f16x8*)&As[(wr * 64 + m * 16 + lr) * 40 + lh * 8];
    #pragma unroll
    for (int n = 0; n < 4; ++n)
      bfr[n] = *(const f16x8*)&Bs[(wc * 64 + n * 16 + lr) * 40 + lh * 8];
    #pragma unroll
    for (int m = 0; m < 4; ++m)
      #pragma unroll
      for (int n = 0; n < 4; ++n)
        acc[m][n] = __builtin_amdgcn_mfma_f32_16x16x32_f16(af[m], bfr[n], acc[m][n], 0, 0, 0);
  }

  #pragma unroll
  for (int n = 0; n < 4; ++n) {
    int col = n0 + wc * 64 + n * 16 + lr;
    float bv_ = bias ? bias[col] : 0.0f;
    #pragma unroll
    for (int m = 0; m < 4; ++m)
      #pragma unroll
      for (int r = 0; r < 4; ++r) {
        int row = m0 + wr * 64 + m * 16 + lh * 4 + r;
        C[(size_t)row * HID + col] = (_Float16)((acc[m][n][r] + bv_) * scale);
      }
  }
}

// ---------------- fused disentangled attention, f16 MFMA, fp32 softmax
// scores pre-scaled by log2(e) at projection -> softmax uses raw v_exp_f32.
// r14 structure + cvt_pkrtz band writes + __builtin_amdgcn_exp2f.
// (r16 configuration: measured best, attn 262us / total 304us)
__global__ __launch_bounds__(256, 2)
void attn_mfma(const _Float16* __restrict__ qg, const _Float16* __restrict__ kg,
               const _Float16* __restrict__ vg, const _Float16* __restrict__ pkg,
               const _Float16* __restrict__ pqg, float* __restrict__ outg) {
  const int q0 = blockIdx.x * 64;
  const int h = blockIdx.y, b = blockIdx.z;
  const int tid = threadIdx.x;
  const int w = tid >> 6, l = tid & 63;
  const int lr = l & 15, lh = l >> 4;
  const size_t hoff = (size_t)h * DH;

  __shared__ _Float16 ks[64 * PSTR];
  __shared__ _Float16 vst[64 * VSTR];   // V^T: vst[d][ki]
  __shared__ _Float16 ps[64 * PSTR];    // P tile, XOR-swizzled nt-blocks
  __shared__ _Float16 posA[128 * PSTR]; // pos_k rows; aliased by c2pT[ri][row]
  __shared__ _Float16 posB[128 * PSTR]; // pos_q rows; aliased by p2cT[ri][row]
  _Float16* c2pT = posA;
  _Float16* p2cT = posB;

  // Q fragments straight from global (loop-invariant)
  f16x8 aq[2];
  #pragma unroll
  for (int kk = 0; kk < 2; ++kk)
    aq[kk] = *(const f16x8*)&qg[((size_t)(b * SEQ + q0 + w * 16 + lr)) * HID + hoff + kk * 32 + lh * 8];

  f32x4 accO[4];
  float m_[4], l_[4];
  #pragma unroll
  for (int r = 0; r < 4; ++r) { m_[r] = -1e30f; l_[r] = 0.0f; }  // l_ per-lane partial
  #pragma unroll
  for (int nt = 0; nt < 4; ++nt) accO[nt] = (f32x4){0.f, 0.f, 0.f, 0.f};

  const int vd4 = tid & 15, vkq = tid >> 4;   // V-staging: 4d x 4k block per thread

  // ---- T14 prefetch registers ----
  f16x8 kreg[2], pAreg[4], pBreg[4];
  f16x4 vreg[4];
  {
    // prologue: load tile 0
    #pragma unroll
    for (int p = 0; p < 2; ++p) {
      int idx = tid + p * 256, row = idx >> 3, c = idx & 7;
      kreg[p] = *(const f16x8*)&kg[((size_t)(b * SEQ + row)) * HID + hoff + c * 8];
    }
    #pragma unroll
    for (int j = 0; j < 4; ++j)
      vreg[j] = *(const f16x4*)&vg[((size_t)(b * SEQ + vkq * 4 + j)) * HID + hoff + vd4 * 4];
    int r_lo1 = min(max(q0 - 63 + SPAN, 0), 2 * SPAN - 1);
    int r_hi1 = min(max(q0 + 63 + SPAN, 0), 2 * SPAN - 1);
    int nr1 = r_hi1 - r_lo1 + 1;
    #pragma unroll
    for (int p = 0; p < 4; ++p) {
      int idx = tid + p * 256;
      if (idx < nr1 * 8) {
        int row = idx >> 3, c = idx & 7;
        size_t gb = ((size_t)(r_lo1 + row)) * HID + hoff + c * 8;
        pAreg[p] = *(const f16x8*)&pkg[gb];
        pBreg[p] = *(const f16x8*)&pqg[gb];
      }
    }
  }

  for (int k0 = 0; k0 < SEQ; k0 += 64) {
    const int r_lo = min(max(q0 - k0 - 63 + SPAN, 0), 2 * SPAN - 1);
    const int r_hi = min(max(q0 - k0 + 63 + SPAN, 0), 2 * SPAN - 1);
    const int nr = r_hi - r_lo + 1;                // <= 127
    const int bt_lim = (nr + 15) >> 4;

    __syncthreads();   // B1: prev-tile PV reads (vst, ps) done
    // ---- LDS writes from prefetched registers ----
    #pragma unroll
    for (int p = 0; p < 2; ++p) {
      int idx = tid + p * 256, row = idx >> 3, c = idx & 7;
      *(f16x8*)&ks[row * PSTR + c * 8] = kreg[p];
    }
    #pragma unroll
    for (int di = 0; di < 4; ++di) {
      f16x4 wv;
      wv.x = vreg[0][di]; wv.y = vreg[1][di]; wv.z = vreg[2][di]; wv.w = vreg[3][di];
      *(f16x4*)&vst[(vd4 * 4 + di) * VSTR + vkq * 4] = wv;
    }
    #pragma unroll
    for (int p = 0; p < 4; ++p) {
      int idx = tid + p * 256;
      if (idx < nr * 8) {
        int row = idx >> 3, c = idx & 7;
        *(f16x8*)&posA[row * PSTR + c * 8] = pAreg[p];
        *(f16x8*)&posB[row * PSTR + c * 8] = pBreg[p];
      }
    }
    // ---- issue next-tile global loads (latency hides under compute) ----
    const int k1 = k0 + 64;
    if (k1 < SEQ) {
      #pragma unroll
      for (int p = 0; p < 2; ++p) {
        int idx = tid + p * 256, row = idx >> 3, c = idx & 7;
        kreg[p] = *(const f16x8*)&kg[((size_t)(b * SEQ + k1 + row)) * HID + hoff + c * 8];
      }
      #pragma unroll
      for (int j = 0; j < 4; ++j)
        vreg[j] = *(const f16x4*)&vg[((size_t)(b * SEQ + k1 + vkq * 4 + j)) * HID + hoff + vd4 * 4];
      int r_lo1 = min(max(q0 - k1 - 63 + SPAN, 0), 2 * SPAN - 1);
      int r_hi1 = min(max(q0 - k1 + 63 + SPAN, 0), 2 * SPAN - 1);
      int nr1 = r_hi1 - r_lo1 + 1;
      #pragma unroll
      for (int p = 0; p < 4; ++p) {
        int idx = tid + p * 256;
        if (idx < nr1 * 8) {
          int row = idx >> 3, c = idx & 7;
          size_t gb = ((size_t)(r_lo1 + row)) * HID + hoff + c * 8;
          pAreg[p] = *(const f16x8*)&pkg[gb];
          pBreg[p] = *(const f16x8*)&pqg[gb];
        }
      }
    }
    __syncthreads();   // B2: ks/vst/pos visible

    // ---- MFMA phase ----
    __builtin_amdgcn_s_setprio(1);
    f16x8 ak[2];
    #pragma unroll
    for (int kk = 0; kk < 2; ++kk)
      ak[kk] = *(const f16x8*)&ks[(w * 16 + lr) * PSTR + kk * 32 + lh * 8];

    f32x4 sqk[4];
    #pragma unroll
    for (int nt = 0; nt < 4; ++nt) sqk[nt] = (f32x4){0.f, 0.f, 0.f, 0.f};
    #pragma unroll
    for (int nt = 0; nt < 4; ++nt)
      #pragma unroll
      for (int kk = 0; kk < 2; ++kk) {
        f16x8 bk = *(const f16x8*)&ks[(nt * 16 + lr) * PSTR + kk * 32 + lh * 8];
        sqk[nt] = __builtin_amdgcn_mfma_f32_16x16x32_f16(aq[kk], bk, sqk[nt], 0, 0, 0);
      }

    f32x4 bandA[8], bandB[8];
    #pragma unroll
    for (int bt = 0; bt < 8; ++bt) {
      bandA[bt] = (f32x4){0.f, 0.f, 0.f, 0.f};
      bandB[bt] = (f32x4){0.f, 0.f, 0.f, 0.f};
    }
    #pragma unroll
    for (int bt = 0; bt < 8; ++bt)
      if (bt < bt_lim)
        #pragma unroll
        for (int kk = 0; kk < 2; ++kk) {
          f16x8 bp = *(const f16x8*)&posA[(bt * 16 + lr) * PSTR + kk * 32 + lh * 8];
          bandA[bt] = __builtin_amdgcn_mfma_f32_16x16x32_f16(aq[kk], bp, bandA[bt], 0, 0, 0);
        }
    #pragma unroll
    for (int bt = 0; bt < 8; ++bt)
      if (bt < bt_lim)
        #pragma unroll
        for (int kk = 0; kk < 2; ++kk) {
          f16x8 bp = *(const f16x8*)&posB[(bt * 16 + lr) * PSTR + kk * 32 + lh * 8];
          bandB[bt] = __builtin_amdgcn_mfma_f32_16x16x32_f16(ak[kk], bp, bandB[bt], 0, 0, 0);
        }
    __builtin_amdgcn_s_setprio(0);
    __syncthreads();  // B3: all frag reads of posA/posB complete

    // ---- write bands TRANSPOSED [ri][row] via cvt_pkrtz (2 VALU per b64) ----
    #pragma unroll
    for (int bt = 0; bt < 8; ++bt)
      if (bt < bt_lim) {
        uint2 wa, wb;
        wa.x = __builtin_bit_cast(unsigned, __builtin_amdgcn_cvt_pkrtz(bandA[bt][0], bandA[bt][1]));
        wa.y = __builtin_bit_cast(unsigned, __builtin_amdgcn_cvt_pkrtz(bandA[bt][2], bandA[bt][3]));
        wb.x = __builtin_bit_cast(unsigned, __builtin_amdgcn_cvt_pkrtz(bandB[bt][0], bandB[bt][1]));
        wb.y = __builtin_bit_cast(unsigned, __builtin_amdgcn_cvt_pkrtz(bandB[bt][2], bandB[bt][3]));
        *(uint2*)&c2pT[(bt * 16 + lr) * PSTR + w * 16 + lh * 4] = wa;
        *(uint2*)&p2cT[(bt * 16 + lr) * PSTR + w * 16 + lh * 4] = wb;
      }
    __syncthreads();   // B4: bands visible to all waves

    // ---- assemble scores, online softmax (raw v_exp_f32, DPP), write P ----
    const int rfix = (q0 - k0 + SPAN) - r_lo;
    float pc1[4];
    if (nr == 1) {
      #pragma unroll
      for (int nt = 0; nt < 4; ++nt) pc1[nt] = (float)p2cT[nt * 16 + lr];
    }
    #pragma unroll
    for (int r = 0; r < 4; ++r) {
      int qi = w * 16 + lh * 4 + r;
      float sc[4];
      if (nr == 1) {
        float cA = (float)c2pT[qi];
        #pragma unroll
        for (int nt = 0; nt < 4; ++nt)
          sc[nt] = sqk[nt][r] + cA + pc1[nt];
      } else {
        #pragma unroll
        for (int nt = 0; nt < 4; ++nt) {
          int ki = nt * 16 + lr;
          int ri = min(max(rfix + qi - ki, 0), nr - 1);
          sc[nt] = sqk[nt][r] + (float)c2pT[ri * PSTR + qi] + (float)p2cT[ri * PSTR + ki];
        }
      }
      float mx = dpp_max16(fmaxf(fmaxf(sc[0], sc[1]), fmaxf(sc[2], sc[3])));
      float mnew = fmaxf(m_[r], mx);
      float alpha = __builtin_amdgcn_exp2f(m_[r] - mnew);   // raw v_exp_f32
      float s0 = 0.0f;
      #pragma unroll
      for (int nt = 0; nt < 4; ++nt) {
        float p = __builtin_amdgcn_exp2f(sc[nt] - mnew);    // raw v_exp_f32
        s0 += p;
        ps[qi * PSTR + ((nt ^ lh) * 16) + lr] = (_Float16)p;   // XOR-swizzled block
      }
      l_[r] = l_[r] * alpha + s0;
      m_[r] = mnew;
      #pragma unroll
      for (int nt = 0; nt < 4; ++nt) accO[nt][r] *= alpha;
    }
    // no barrier: ps rows and pa reads are wave-local; vst unchanged since stage

    // ---- PV: O[16 q-rows][64 d] += P[16][64] @ V[64][64] ----
    __builtin_amdgcn_s_setprio(1);
    f16x8 pa[2];
    const int keyr = lr >> 2;                     // (row>>2)&3 for row = w*16+lr
    #pragma unroll
    for (int kk = 0; kk < 2; ++kk) {
      int blk = (kk * 2 + (lh >> 1)) ^ keyr;      // inverse of nt^lh write perm
      pa[kk] = *(const f16x8*)&ps[(w * 16 + lr) * PSTR + blk * 16 + (lh & 1) * 8];
    }
    #pragma unroll
    for (int nt = 0; nt < 4; ++nt)
      #pragma unroll
      for (int kk = 0; kk < 2; ++kk) {
        f16x8 vb = *(const f16x8*)&vst[(nt * 16 + lr) * VSTR + kk * 32 + lh * 8];
        accO[nt] = __builtin_amdgcn_mfma_f32_16x16x32_f16(pa[kk], vb, accO[nt], 0, 0, 0);
      }
    __builtin_amdgcn_s_setprio(0);
  }

  // ---- output (reduce per-lane partial l via DPP) ----
  #pragma unroll
  for (int r = 0; r < 4; ++r) {
    float inv = 1.0f / dpp_sum16(l_[r]);
    int row = q0 + w * 16 + lh * 4 + r;
    #pragma unroll
    for (int nt = 0; nt < 4; ++nt) {
      int col = h * DH + nt * 16 + lr;
      outg[((size_t)(b * SEQ + row)) * HID + col] = accO[nt][r] * inv;
    }
  }
}

extern "C" void kernel_launch(void* const* d_in, const int* in_sizes, int n_in,
                              void* d_out, int out_size, void* d_ws, size_t ws_size,
                              hipStream_t stream) {
  const float* hs  = (const float*)d_in[0];
  const float* rel = (const float*)d_in[1];
  const float* Wq  = (const float*)d_in[2];
  const float* bq  = (const float*)d_in[3];
  const float* Wk  = (const float*)d_in[4];
  const float* bk  = (const float*)d_in[5];
  const float* Wv  = (const float*)d_in[6];
  const float* bv  = (const float*)d_in[7];
  const float* Wpk = (const float*)d_in[8];
  const float* Wpq = (const float*)d_in[9];
  const float* bpq = (const float*)d_in[10];
  float* out = (float*)d_out;

  _Float16* ws = (_Float16*)d_ws;
  _Float16* q   = ws;                         // 4096x1024 f16
  _Float16* k   = ws + 4194304;
  _Float16* v   = ws + 8388608;
  _Float16* pk  = ws + 12582912;              // 1024x1024 f16
  _Float16* pq  = ws + 13631488;
  _Float16* A16 = ws + 14680064;              // hs f16
  _Float16* R16 = ws + 18874368;              // rel f16
  _Float16* Wt  = ws + 19922944;              // 5x 1024x1024 f16 (transposed W)

  const float LOG2E = 1.44269504088896f;
  // log2(e) folded into q and pos_q so softmax runs on raw v_exp_f32:
  // qk, c2p scale via q; p2c scale via pos_q -> ALL score terms in log2 units.
  const float qscale  = 0.125f * LOG2E;                          // 1/sqrt(64) * log2e
  const float pqscale = (1.0f / (8.0f * sqrtf(192.0f))) * LOG2E;

  dim3 blk(256);
  cvt16<<<dim3(2048), blk, 0, stream>>>(hs, A16, (NB * SEQ * HID) / 4);
  cvt16<<<dim3(1024), blk, 0, stream>>>(rel, R16, (2 * SPAN * HID) / 4);
  transW<<<dim3(16, 16, 5), blk, 0, stream>>>(Wq, Wk, Wv, Wpk, Wpq, Wt);

  gemm_all<<<dim3(HID / 128, (NB * SEQ) / 128, 5), blk, 0, stream>>>(
      A16, R16, Wt, bq, bk, bv, bpq, q, k, v, pk, pq, qscale, pqscale);

  dim3 ga(SEQ / 64, NH, NB);
  attn_mfma<<<ga, blk, 0, stream>>>(q, k, v, pk, pq, out);
}

// Round 20
// 301.334 us; speedup vs baseline: 2.2897x; 1.0090x over previous
//
#include <hip/hip_runtime.h>
#include <math.h>

#define HID 1024
#define NH 16
#define DH 64
#define SEQ 2048
#define NB 2
#define SPAN 512
#define PSTR 72    // ks/ps/pos row stride (144 B)
#define VSTR 66    // vst stride (odd dword stride -> bank spread)

typedef __attribute__((ext_vector_type(8))) _Float16 f16x8;
typedef __attribute__((ext_vector_type(4))) _Float16 f16x4;
typedef __attribute__((ext_vector_type(4))) float f32x4;

// DPP ROW_ROR butterfly reduce over 16-lane rows (VALU pipe, no LDS traffic)
__device__ __forceinline__ float dpp_max16(float x) {
  int v;
  v = __builtin_amdgcn_update_dpp(0, __builtin_bit_cast(int, x), 0x128, 0xF, 0xF, true);
  x = fmaxf(x, __builtin_bit_cast(float, v));
  v = __builtin_amdgcn_update_dpp(0, __builtin_bit_cast(int, x), 0x124, 0xF, 0xF, true);
  x = fmaxf(x, __builtin_bit_cast(float, v));
  v = __builtin_amdgcn_update_dpp(0, __builtin_bit_cast(int, x), 0x122, 0xF, 0xF, true);
  x = fmaxf(x, __builtin_bit_cast(float, v));
  v = __builtin_amdgcn_update_dpp(0, __builtin_bit_cast(int, x), 0x121, 0xF, 0xF, true);
  return fmaxf(x, __builtin_bit_cast(float, v));
}
__device__ __forceinline__ float dpp_sum16(float x) {
  int v;
  v = __builtin_amdgcn_update_dpp(0, __builtin_bit_cast(int, x), 0x128, 0xF, 0xF, true);
  x += __builtin_bit_cast(float, v);
  v = __builtin_amdgcn_update_dpp(0, __builtin_bit_cast(int, x), 0x124, 0xF, 0xF, true);
  x += __builtin_bit_cast(float, v);
  v = __builtin_amdgcn_update_dpp(0, __builtin_bit_cast(int, x), 0x122, 0xF, 0xF, true);
  x += __builtin_bit_cast(float, v);
  v = __builtin_amdgcn_update_dpp(0, __builtin_bit_cast(int, x), 0x121, 0xF, 0xF, true);
  return x + __builtin_bit_cast(float, v);
}

// ---------------- f32 -> f16 convert (n4 = n/4)
__global__ __launch_bounds__(256)
void cvt16(const float* __restrict__ src, _Float16* __restrict__ dst, int n4) {
  int i = blockIdx.x * 256 + threadIdx.x;
  const int stride = gridDim.x * 256;
  for (; i < n4; i += stride) {
    float4 v = ((const float4*)src)[i];
    f16x4 o;
    o.x = (_Float16)v.x; o.y = (_Float16)v.y;
    o.z = (_Float16)v.z; o.w = (_Float16)v.w;
    ((f16x4*)dst)[i] = o;
  }
}

// ---------------- transpose+convert: Wt[z][n][k] = (f16) W_z[k][n]
__global__ __launch_bounds__(256)
void transW(const float* __restrict__ W0, const float* __restrict__ W1,
            const float* __restrict__ W2, const float* __restrict__ W3,
            const float* __restrict__ W4, _Float16* __restrict__ Wt) {
  const int z = blockIdx.z;
  const float* W = z == 0 ? W0 : z == 1 ? W1 : z == 2 ? W2 : z == 3 ? W3 : W4;
  _Float16* out = Wt + (size_t)z * HID * HID;
  const int k0 = blockIdx.x * 64, n0 = blockIdx.y * 64;
  __shared__ _Float16 t[64][72];
  const int tid = threadIdx.x;
  #pragma unroll
  for (int p = 0; p < 4; ++p) {
    int idx = tid + p * 256;
    int row = idx >> 4, c4 = idx & 15;
    float4 v = *(const float4*)&W[(size_t)(k0 + row) * HID + n0 + c4 * 4];
    t[c4 * 4 + 0][row] = (_Float16)v.x;
    t[c4 * 4 + 1][row] = (_Float16)v.y;
    t[c4 * 4 + 2][row] = (_Float16)v.z;
    t[c4 * 4 + 3][row] = (_Float16)v.w;
  }
  __syncthreads();
  #pragma unroll
  for (int p = 0; p < 2; ++p) {
    int idx = tid + p * 256;
    int row = idx >> 3, c8 = idx & 7;
    *(f16x8*)&out[(size_t)(n0 + row) * HID + k0 + c8 * 8] = *(const f16x8*)&t[row][c8 * 8];
  }
}

// ---------------- fused f16-MFMA GEMM for all 5 projections (z selects)
__global__ __launch_bounds__(256)
void gemm_all(const _Float16* __restrict__ A16, const _Float16* __restrict__ R16,
              const _Float16* __restrict__ Wt,
              const float* __restrict__ bq, const float* __restrict__ bk,
              const float* __restrict__ bv, const float* __restrict__ bpq,
              _Float16* __restrict__ qo, _Float16* __restrict__ ko,
              _Float16* __restrict__ vo, _Float16* __restrict__ pko,
              _Float16* __restrict__ pqo, float qscale, float pqscale) {
  const int z = blockIdx.z;
  if (z >= 3 && blockIdx.y >= 8) return;          // pos GEMMs: M=1024 only
  const _Float16* A = (z < 3) ? A16 : R16;
  const _Float16* B = Wt + (size_t)z * HID * HID;
  const float* bias = z == 0 ? bq : z == 1 ? bk : z == 2 ? bv : z == 3 ? (const float*)nullptr : bpq;
  _Float16* C = z == 0 ? qo : z == 1 ? ko : z == 2 ? vo : z == 3 ? pko : pqo;
  const float scale = z == 0 ? qscale : z == 4 ? pqscale : 1.0f;

  __shared__ _Float16 As[128 * 40];
  __shared__ _Float16 Bs[128 * 40];
  const int tid = threadIdx.x;
  const int m0 = blockIdx.y * 128, n0 = blockIdx.x * 128;
  const int w = tid >> 6, l = tid & 63;
  const int wr = w >> 1, wc = w & 1;
  const int lr = l & 15, lh = l >> 4;

  f32x4 acc[4][4];
  #pragma unroll
  for (int m = 0; m < 4; ++m)
    #pragma unroll
    for (int n = 0; n < 4; ++n)
      acc[m][n] = (f32x4){0.f, 0.f, 0.f, 0.f};

  for (int k0 = 0; k0 < HID; k0 += 32) {
    __syncthreads();
    #pragma unroll
    for (int p = 0; p < 2; ++p) {
      int idx = tid + p * 256;
      int row = idx >> 2, c = idx & 3;
      *(f16x8*)&As[row * 40 + c * 8] = *(const f16x8*)&A[(size_t)(m0 + row) * HID + k0 + c * 8];
      *(f16x8*)&Bs[row * 40 + c * 8] = *(const f16x8*)&B[(size_t)(n0 + row) * HID + k0 + c * 8];
    }
    __syncthreads();

    f16x8 af[4], bfr[4];
    #pragma unroll
    for (int m = 0; m < 4; ++m)
      af[m] = *(const f16x8*)&As[(wr * 64 + m * 16 + lr) * 40 + lh * 8];
    #pragma unroll
    for (int n = 0; n < 4; ++n)
      bfr[n] = *(const f16x8*)&Bs[(wc * 64 + n * 16 + lr) * 40 + lh * 8];
    #pragma unroll
    for (int m = 0; m < 4; ++m)
      #pragma unroll
      for (int n = 0; n < 4; ++n)
        acc[m][n] = __builtin_amdgcn_mfma_f32_16x16x32_f16(af[m], bfr[n], acc[m][n], 0, 0, 0);
  }

  #pragma unroll
  for (int n = 0; n < 4; ++n) {
    int col = n0 + wc * 64 + n * 16 + lr;
    float bv_ = bias ? bias[col] : 0.0f;
    #pragma unroll
    for (int m = 0; m < 4; ++m)
      #pragma unroll
      for (int r = 0; r < 4; ++r) {
        int row = m0 + wr * 64 + m * 16 + lh * 4 + r;
        C[(size_t)row * HID + col] = (_Float16)((acc[m][n][r] + bv_) * scale);
      }
  }
}

// ---------------- fused disentangled attention, f16 MFMA, fp32 softmax
// r16 configuration (measured best) + XCD-aware block swizzle: each XCD gets
// 128 contiguous logical blocks = 4 complete (h,b) groups -> K/V/pos L2-local.
__global__ __launch_bounds__(256, 2)
void attn_mfma(const _Float16* __restrict__ qg, const _Float16* __restrict__ kg,
               const _Float16* __restrict__ vg, const _Float16* __restrict__ pkg,
               const _Float16* __restrict__ pqg, float* __restrict__ outg) {
  // bijective XCD swizzle: physical p -> logical (p%8)*128 + p/8  (nwg=1024)
  const int pblk = blockIdx.x;
  const int logical = (pblk & 7) * 128 + (pblk >> 3);
  const int q0 = (logical & 31) * 64;
  const int h = (logical >> 5) & 15;
  const int b = logical >> 9;
  const int tid = threadIdx.x;
  const int w = tid >> 6, l = tid & 63;
  const int lr = l & 15, lh = l >> 4;
  const size_t hoff = (size_t)h * DH;

  __shared__ _Float16 ks[64 * PSTR];
  __shared__ _Float16 vst[64 * VSTR];   // V^T: vst[d][ki]
  __shared__ _Float16 ps[64 * PSTR];    // P tile, XOR-swizzled nt-blocks
  __shared__ _Float16 posA[128 * PSTR]; // pos_k rows; aliased by c2pT[ri][row]
  __shared__ _Float16 posB[128 * PSTR]; // pos_q rows; aliased by p2cT[ri][row]
  _Float16* c2pT = posA;
  _Float16* p2cT = posB;

  // Q fragments straight from global (loop-invariant)
  f16x8 aq[2];
  #pragma unroll
  for (int kk = 0; kk < 2; ++kk)
    aq[kk] = *(const f16x8*)&qg[((size_t)(b * SEQ + q0 + w * 16 + lr)) * HID + hoff + kk * 32 + lh * 8];

  f32x4 accO[4];
  float m_[4], l_[4];
  #pragma unroll
  for (int r = 0; r < 4; ++r) { m_[r] = -1e30f; l_[r] = 0.0f; }  // l_ per-lane partial
  #pragma unroll
  for (int nt = 0; nt < 4; ++nt) accO[nt] = (f32x4){0.f, 0.f, 0.f, 0.f};

  const int vd4 = tid & 15, vkq = tid >> 4;   // V-staging: 4d x 4k block per thread

  // ---- T14 prefetch registers ----
  f16x8 kreg[2], pAreg[4], pBreg[4];
  f16x4 vreg[4];
  {
    // prologue: load tile 0
    #pragma unroll
    for (int p = 0; p < 2; ++p) {
      int idx = tid + p * 256, row = idx >> 3, c = idx & 7;
      kreg[p] = *(const f16x8*)&kg[((size_t)(b * SEQ + row)) * HID + hoff + c * 8];
    }
    #pragma unroll
    for (int j = 0; j < 4; ++j)
      vreg[j] = *(const f16x4*)&vg[((size_t)(b * SEQ + vkq * 4 + j)) * HID + hoff + vd4 * 4];
    int r_lo1 = min(max(q0 - 63 + SPAN, 0), 2 * SPAN - 1);
    int r_hi1 = min(max(q0 + 63 + SPAN, 0), 2 * SPAN - 1);
    int nr1 = r_hi1 - r_lo1 + 1;
    #pragma unroll
    for (int p = 0; p < 4; ++p) {
      int idx = tid + p * 256;
      if (idx < nr1 * 8) {
        int row = idx >> 3, c = idx & 7;
        size_t gb = ((size_t)(r_lo1 + row)) * HID + hoff + c * 8;
        pAreg[p] = *(const f16x8*)&pkg[gb];
        pBreg[p] = *(const f16x8*)&pqg[gb];
      }
    }
  }

  for (int k0 = 0; k0 < SEQ; k0 += 64) {
    const int r_lo = min(max(q0 - k0 - 63 + SPAN, 0), 2 * SPAN - 1);
    const int r_hi = min(max(q0 - k0 + 63 + SPAN, 0), 2 * SPAN - 1);
    const int nr = r_hi - r_lo + 1;                // <= 127
    const int bt_lim = (nr + 15) >> 4;

    __syncthreads();   // B1: prev-tile PV reads (vst, ps) done
    // ---- LDS writes from prefetched registers ----
    #pragma unroll
    for (int p = 0; p < 2; ++p) {
      int idx = tid + p * 256, row = idx >> 3, c = idx & 7;
      *(f16x8*)&ks[row * PSTR + c * 8] = kreg[p];
    }
    #pragma unroll
    for (int di = 0; di < 4; ++di) {
      f16x4 wv;
      wv.x = vreg[0][di]; wv.y = vreg[1][di]; wv.z = vreg[2][di]; wv.w = vreg[3][di];
      *(f16x4*)&vst[(vd4 * 4 + di) * VSTR + vkq * 4] = wv;
    }
    #pragma unroll
    for (int p = 0; p < 4; ++p) {
      int idx = tid + p * 256;
      if (idx < nr * 8) {
        int row = idx >> 3, c = idx & 7;
        *(f16x8*)&posA[row * PSTR + c * 8] = pAreg[p];
        *(f16x8*)&posB[row * PSTR + c * 8] = pBreg[p];
      }
    }
    // ---- issue next-tile global loads (latency hides under compute) ----
    const int k1 = k0 + 64;
    if (k1 < SEQ) {
      #pragma unroll
      for (int p = 0; p < 2; ++p) {
        int idx = tid + p * 256, row = idx >> 3, c = idx & 7;
        kreg[p] = *(const f16x8*)&kg[((size_t)(b * SEQ + k1 + row)) * HID + hoff + c * 8];
      }
      #pragma unroll
      for (int j = 0; j < 4; ++j)
        vreg[j] = *(const f16x4*)&vg[((size_t)(b * SEQ + k1 + vkq * 4 + j)) * HID + hoff + vd4 * 4];
      int r_lo1 = min(max(q0 - k1 - 63 + SPAN, 0), 2 * SPAN - 1);
      int r_hi1 = min(max(q0 - k1 + 63 + SPAN, 0), 2 * SPAN - 1);
      int nr1 = r_hi1 - r_lo1 + 1;
      #pragma unroll
      for (int p = 0; p < 4; ++p) {
        int idx = tid + p * 256;
        if (idx < nr1 * 8) {
          int row = idx >> 3, c = idx & 7;
          size_t gb = ((size_t)(r_lo1 + row)) * HID + hoff + c * 8;
          pAreg[p] = *(const f16x8*)&pkg[gb];
          pBreg[p] = *(const f16x8*)&pqg[gb];
        }
      }
    }
    __syncthreads();   // B2: ks/vst/pos visible

    // ---- MFMA phase ----
    __builtin_amdgcn_s_setprio(1);
    f16x8 ak[2];
    #pragma unroll
    for (int kk = 0; kk < 2; ++kk)
      ak[kk] = *(const f16x8*)&ks[(w * 16 + lr) * PSTR + kk * 32 + lh * 8];

    f32x4 sqk[4];
    #pragma unroll
    for (int nt = 0; nt < 4; ++nt) sqk[nt] = (f32x4){0.f, 0.f, 0.f, 0.f};
    #pragma unroll
    for (int nt = 0; nt < 4; ++nt)
      #pragma unroll
      for (int kk = 0; kk < 2; ++kk) {
        f16x8 bk = *(const f16x8*)&ks[(nt * 16 + lr) * PSTR + kk * 32 + lh * 8];
        sqk[nt] = __builtin_amdgcn_mfma_f32_16x16x32_f16(aq[kk], bk, sqk[nt], 0, 0, 0);
      }

    f32x4 bandA[8], bandB[8];
    #pragma unroll
    for (int bt = 0; bt < 8; ++bt) {
      bandA[bt] = (f32x4){0.f, 0.f, 0.f, 0.f};
      bandB[bt] = (f32x4){0.f, 0.f, 0.f, 0.f};
    }
    #pragma unroll
    for (int bt = 0; bt < 8; ++bt)
      if (bt < bt_lim)
        #pragma unroll
        for (int kk = 0; kk < 2; ++kk) {
          f16x8 bp = *(const f16x8*)&posA[(bt * 16 + lr) * PSTR + kk * 32 + lh * 8];
          bandA[bt] = __builtin_amdgcn_mfma_f32_16x16x32_f16(aq[kk], bp, bandA[bt], 0, 0, 0);
        }
    #pragma unroll
    for (int bt = 0; bt < 8; ++bt)
      if (bt < bt_lim)
        #pragma unroll
        for (int kk = 0; kk < 2; ++kk) {
          f16x8 bp = *(const f16x8*)&posB[(bt * 16 + lr) * PSTR + kk * 32 + lh * 8];
          bandB[bt] = __builtin_amdgcn_mfma_f32_16x16x32_f16(ak[kk], bp, bandB[bt], 0, 0, 0);
        }
    __builtin_amdgcn_s_setprio(0);
    __syncthreads();  // B3: all frag reads of posA/posB complete

    // ---- write bands TRANSPOSED [ri][row] via cvt_pkrtz (2 VALU per b64) ----
    #pragma unroll
    for (int bt = 0; bt < 8; ++bt)
      if (bt < bt_lim) {
        uint2 wa, wb;
        wa.x = __builtin_bit_cast(unsigned, __builtin_amdgcn_cvt_pkrtz(bandA[bt][0], bandA[bt][1]));
        wa.y = __builtin_bit_cast(unsigned, __builtin_amdgcn_cvt_pkrtz(bandA[bt][2], bandA[bt][3]));
        wb.x = __builtin_bit_cast(unsigned, __builtin_amdgcn_cvt_pkrtz(bandB[bt][0], bandB[bt][1]));
        wb.y = __builtin_bit_cast(unsigned, __builtin_amdgcn_cvt_pkrtz(bandB[bt][2], bandB[bt][3]));
        *(uint2*)&c2pT[(bt * 16 + lr) * PSTR + w * 16 + lh * 4] = wa;
        *(uint2*)&p2cT[(bt * 16 + lr) * PSTR + w * 16 + lh * 4] = wb;
      }
    __syncthreads();   // B4: bands visible to all waves

    // ---- assemble scores, online softmax (raw v_exp_f32, DPP), write P ----
    const int rfix = (q0 - k0 + SPAN) - r_lo;
    float pc1[4];
    if (nr == 1) {
      #pragma unroll
      for (int nt = 0; nt < 4; ++nt) pc1[nt] = (float)p2cT[nt * 16 + lr];
    }
    #pragma unroll
    for (int r = 0; r < 4; ++r) {
      int qi = w * 16 + lh * 4 + r;
      float sc[4];
      if (nr == 1) {
        float cA = (float)c2pT[qi];
        #pragma unroll
        for (int nt = 0; nt < 4; ++nt)
          sc[nt] = sqk[nt][r] + cA + pc1[nt];
      } else {
        #pragma unroll
        for (int nt = 0; nt < 4; ++nt) {
          int ki = nt * 16 + lr;
          int ri = min(max(rfix + qi - ki, 0), nr - 1);
          sc[nt] = sqk[nt][r] + (float)c2pT[ri * PSTR + qi] + (float)p2cT[ri * PSTR + ki];
        }
      }
      float mx = dpp_max16(fmaxf(fmaxf(sc[0], sc[1]), fmaxf(sc[2], sc[3])));
      float mnew = fmaxf(m_[r], mx);
      float alpha = __builtin_amdgcn_exp2f(m_[r] - mnew);   // raw v_exp_f32
      float s0 = 0.0f;
      #pragma unroll
      for (int nt = 0; nt < 4; ++nt) {
        float p = __builtin_amdgcn_exp2f(sc[nt] - mnew);    // raw v_exp_f32
        s0 += p;
        ps[qi * PSTR + ((nt ^ lh) * 16) + lr] = (_Float16)p;   // XOR-swizzled block
      }
      l_[r] = l_[r] * alpha + s0;
      m_[r] = mnew;
      #pragma unroll
      for (int nt = 0; nt < 4; ++nt) accO[nt][r] *= alpha;
    }
    // no barrier: ps rows and pa reads are wave-local; vst unchanged since stage

    // ---- PV: O[16 q-rows][64 d] += P[16][64] @ V[64][64] ----
    __builtin_amdgcn_s_setprio(1);
    f16x8 pa[2];
    const int keyr = lr >> 2;                     // (row>>2)&3 for row = w*16+lr
    #pragma unroll
    for (int kk = 0; kk < 2; ++kk) {
      int blk = (kk * 2 + (lh >> 1)) ^ keyr;      // inverse of nt^lh write perm
      pa[kk] = *(const f16x8*)&ps[(w * 16 + lr) * PSTR + blk * 16 + (lh & 1) * 8];
    }
    #pragma unroll
    for (int nt = 0; nt < 4; ++nt)
      #pragma unroll
      for (int kk = 0; kk < 2; ++kk) {
        f16x8 vb = *(const f16x8*)&vst[(nt * 16 + lr) * VSTR + kk * 32 + lh * 8];
        accO[nt] = __builtin_amdgcn_mfma_f32_16x16x32_f16(pa[kk], vb, accO[nt], 0, 0, 0);
      }
    __builtin_amdgcn_s_setprio(0);
  }

  // ---- output (reduce per-lane partial l via DPP) ----
  #pragma unroll
  for (int r = 0; r < 4; ++r) {
    float inv = 1.0f / dpp_sum16(l_[r]);
    int row = q0 + w * 16 + lh * 4 + r;
    #pragma unroll
    for (int nt = 0; nt < 4; ++nt) {
      int col = h * DH + nt * 16 + lr;
      outg[((size_t)(b * SEQ + row)) * HID + col] = accO[nt][r] * inv;
    }
  }
}

extern "C" void kernel_launch(void* const* d_in, const int* in_sizes, int n_in,
                              void* d_out, int out_size, void* d_ws, size_t ws_size,
                              hipStream_t stream) {
  const float* hs  = (const float*)d_in[0];
  const float* rel = (const float*)d_in[1];
  const float* Wq  = (const float*)d_in[2];
  const float* bq  = (const float*)d_in[3];
  const float* Wk  = (const float*)d_in[4];
  const float* bk  = (const float*)d_in[5];
  const float* Wv  = (const float*)d_in[6];
  const float* bv  = (const float*)d_in[7];
  const float* Wpk = (const float*)d_in[8];
  const float* Wpq = (const float*)d_in[9];
  const float* bpq = (const float*)d_in[10];
  float* out = (float*)d_out;

  _Float16* ws = (_Float16*)d_ws;
  _Float16* q   = ws;                         // 4096x1024 f16
  _Float16* k   = ws + 4194304;
  _Float16* v   = ws + 8388608;
  _Float16* pk  = ws + 12582912;              // 1024x1024 f16
  _Float16* pq  = ws + 13631488;
  _Float16* A16 = ws + 14680064;              // hs f16
  _Float16* R16 = ws + 18874368;              // rel f16
  _Float16* Wt  = ws + 19922944;              // 5x 1024x1024 f16 (transposed W)

  const float LOG2E = 1.44269504088896f;
  // log2(e) folded into q and pos_q so softmax runs on raw v_exp_f32:
  // qk, c2p scale via q; p2c scale via pos_q -> ALL score terms in log2 units.
  const float qscale  = 0.125f * LOG2E;                          // 1/sqrt(64) * log2e
  const float pqscale = (1.0f / (8.0f * sqrtf(192.0f))) * LOG2E;

  dim3 blk(256);
  cvt16<<<dim3(2048), blk, 0, stream>>>(hs, A16, (NB * SEQ * HID) / 4);
  cvt16<<<dim3(1024), blk, 0, stream>>>(rel, R16, (2 * SPAN * HID) / 4);
  transW<<<dim3(16, 16, 5), blk, 0, stream>>>(Wq, Wk, Wv, Wpk, Wpq, Wt);

  gemm_all<<<dim3(HID / 128, (NB * SEQ) / 128, 5), blk, 0, stream>>>(
      A16, R16, Wt, bq, bk, bv, bpq, q, k, v, pk, pq, qscale, pqscale);

  // 1D grid with XCD-aware swizzle decoded in-kernel (1024 blocks, nwg%8==0)
  attn_mfma<<<dim3(32 * NH * NB), blk, 0, stream>>>(q, k, v, pk, pq, out);
}